// Round 1
// baseline (299.529 us; speedup 1.0000x reference)
//
#include <hip/hip_runtime.h>
#include <math.h>

#define TPB 256

// One wave = 4 groups of 16 lanes; each group now owns FOUR rows (wave = 16
// rows, block = 64 rows). The 6 ds_read_b128 weight reads per t-step are
// amortized over 16 rows (was 4), cutting LDS-pipe cycles/row ~4x — the
// kernel is HBM-read-bound (205.5 MB) and LDS issue was ~72% of the HBM
// time, polluting the overlap. 4 independent row-loads per lane per t also
// quadruple in-flight global bytes per wave.
__global__ __launch_bounds__(TPB) void hybrid_kernel(
    const float* __restrict__ inp,   // (B, 784)
    const float* __restrict__ dw,    // (784, 6)
    const float* __restrict__ db,    // (6,)
    const float* __restrict__ qw,    // (15,)
    const float* __restrict__ ow,    // (6, 1)
    const float* __restrict__ ob,    // (1,)
    float* __restrict__ out,         // (B, 1)
    int B)
{
    __shared__ float4 wT4[6 * 196];          // wT[j][e] as float4 along e
    __shared__ float csc[15], css[15];
    __shared__ float sb[8], sw[8];
    __shared__ float sob;

    float* wT = (float*)wT4;
    const int tid = threadIdx.x;

    // ---- once per block: transpose dense_w into LDS, precompute cos/sin ----
    for (int i = tid; i < 4704; i += TPB) {   // 784*6
        int e = i / 6;
        int j = i - e * 6;
        wT[j * 784 + e] = dw[i];
    }
    if (tid < 15) { float q = qw[tid]; csc[tid] = cosf(q); css[tid] = sinf(q); }
    if (tid < 6)  { sb[tid] = db[tid]; sw[tid] = ow[tid]; }
    if (tid == 0) sob = ob[0];
    __syncthreads();

    const int lane = tid & 63;
    const int grp  = lane >> 4;       // 0..3 : which row-group within the wave
    const int gl   = lane & 15;       // lane within the 16-lane group
    const int row0 = blockIdx.x * 64 + (tid >> 6) * 16 + grp * 4;
    if (row0 >= B) return;            // no further barriers below

    // clamp row pointers for a (non-occurring at B=65536) ragged tail;
    // stores are guarded per-row below.
    const int r1 = (row0 + 1 < B) ? row0 + 1 : row0;
    const int r2 = (row0 + 2 < B) ? row0 + 2 : row0;
    const int r3 = (row0 + 3 < B) ? row0 + 3 : row0;

    const float4* x0 = (const float4*)(inp + (size_t)row0 * 784);
    const float4* x1 = (const float4*)(inp + (size_t)r1   * 784);
    const float4* x2 = (const float4*)(inp + (size_t)r2   * 784);
    const float4* x3 = (const float4*)(inp + (size_t)r3   * 784);

    float acc[4][6] = {};

    // 196 float4 per row: 12 full passes of 16 lanes + 4-lane tail
    #pragma unroll 2
    for (int t = 0; t < 12; ++t) {
        const int idx4 = gl + 16 * t;
        const float4 a0 = x0[idx4];
        const float4 a1 = x1[idx4];
        const float4 a2 = x2[idx4];
        const float4 a3 = x3[idx4];
        #pragma unroll
        for (int j = 0; j < 6; ++j) {
            const float4 wv = wT4[j * 196 + idx4];
            acc[0][j] += a0.x * wv.x + a0.y * wv.y + a0.z * wv.z + a0.w * wv.w;
            acc[1][j] += a1.x * wv.x + a1.y * wv.y + a1.z * wv.z + a1.w * wv.w;
            acc[2][j] += a2.x * wv.x + a2.y * wv.y + a2.z * wv.z + a2.w * wv.w;
            acc[3][j] += a3.x * wv.x + a3.y * wv.y + a3.z * wv.z + a3.w * wv.w;
        }
    }
    if (gl < 4) {
        const int idx4 = 192 + gl;
        const float4 a0 = x0[idx4];
        const float4 a1 = x1[idx4];
        const float4 a2 = x2[idx4];
        const float4 a3 = x3[idx4];
        #pragma unroll
        for (int j = 0; j < 6; ++j) {
            const float4 wv = wT4[j * 196 + idx4];
            acc[0][j] += a0.x * wv.x + a0.y * wv.y + a0.z * wv.z + a0.w * wv.w;
            acc[1][j] += a1.x * wv.x + a1.y * wv.y + a1.z * wv.z + a1.w * wv.w;
            acc[2][j] += a2.x * wv.x + a2.y * wv.y + a2.z * wv.z + a2.w * wv.w;
            acc[3][j] += a3.x * wv.x + a3.y * wv.y + a3.z * wv.z + a3.w * wv.w;
        }
    }

    // reduce across the 16-lane group (masks 1,2,4,8 stay inside the group)
    #pragma unroll
    for (int m = 1; m <= 8; m <<= 1) {
        #pragma unroll
        for (int r = 0; r < 4; ++r) {
            #pragma unroll
            for (int j = 0; j < 6; ++j)
                acc[r][j] += __shfl_xor(acc[r][j], m, 64);
        }
    }

    // ---- epilogue per row (redundant across the 16 lanes; gl==0 stores) ----
    // PYRAMID_PAIRS: second index is always first+1
    const int PI[15] = {0,1,0,2,1,3,0,2,4,1,3,0,2,1,0};

    #pragma unroll
    for (int r = 0; r < 4; ++r) {
        float a[6];
        float hh = 0.f;
        #pragma unroll
        for (int j = 0; j < 6; ++j) {
            a[j] = acc[r][j] + sb[j];
            hh += a[j] * a[j];
        }
        const float inv = rsqrtf(hh);   // hh==0 -> inf -> NaN downstream, matches ref
        #pragma unroll
        for (int j = 0; j < 6; ++j) a[j] *= inv;

        #pragma unroll
        for (int k = 0; k < 15; ++k) {
            const int i = PI[k];
            const float c = csc[k], s = css[k];
            const float ai = a[i], aj = a[i + 1];
            a[i]     = c * ai + s * aj;
            a[i + 1] = c * aj - s * ai;
        }

        float v = sob;
        #pragma unroll
        for (int j = 0; j < 6; ++j) {
            float z = 1.f - 2.f * a[j] * a[j];
            z = isnan(z) ? 0.f : z;     // jnp.where(isnan(z), 0, z)
            v += z * sw[j];
        }
        const float o = 1.f / (1.f + __expf(-v));

        if (gl == 0 && row0 + r < B) out[row0 + r] = o;
    }
}

extern "C" void kernel_launch(void* const* d_in, const int* in_sizes, int n_in,
                              void* d_out, int out_size, void* d_ws, size_t ws_size,
                              hipStream_t stream) {
    const float* inp = (const float*)d_in[0];
    const float* dw  = (const float*)d_in[1];
    const float* db  = (const float*)d_in[2];
    const float* qw  = (const float*)d_in[3];
    const float* ow  = (const float*)d_in[4];
    const float* ob  = (const float*)d_in[5];
    float* out = (float*)d_out;

    const int B = in_sizes[0] / 784;          // 65536
    const int blocks = (B + 63) / 64;         // 64 rows per block
    hybrid_kernel<<<blocks, TPB, 0, stream>>>(inp, dw, db, qw, ow, ob, out, B);
}

// Round 2
// 297.663 us; speedup vs baseline: 1.0063x; 1.0063x over previous
//
#include <hip/hip_runtime.h>
#include <math.h>

#define TPB 64      // one wave per block; 1024 blocks -> 4 blocks/CU
#define CH  14      // float4-steps per chunk
#define NC  14      // 14*14 = 196 float4 = 784 floats per row

// Row-per-thread: each lane owns one full input row. All lanes walk elements
// in lockstep, so the weight address depends only on the (unrolled) loop
// counter -> wave-uniform -> compiler emits s_load through the scalar cache
// (dense_w = 4.7 KB, K$-resident). Weights cost zero VMEM/LDS/VALU.
// No LDS, no shuffles, no barriers; epilogue once per row (was 16x redundant).
// Occupancy is 1 wave/SIMD (65536 rows = 1024 waves), so latency hiding is
// pure ILP: explicit 14-deep float4 double-buffer = 14 KB/wave in flight.
// Per-lane 16B loads at 3136 B stride reuse each 64B line over 4 consecutive
// steps; working set 64 lanes x 1 line = 4-8 KB/wave -> L1-resident, no
// HBM over-fetch.

#define LOAD_CHUNK(BUF, CBASE)                                   \
    _Pragma("unroll")                                            \
    for (int i = 0; i < CH; ++i) BUF[i] = x4[(CBASE) * CH + i];

#define COMP_CHUNK(BUF, CBASE)                                   \
    _Pragma("unroll")                                            \
    for (int i = 0; i < CH; ++i) {                               \
        const float* wp = dw + (size_t)(((CBASE) * CH + i) * 24);\
        const float4 xv = BUF[i];                                \
        _Pragma("unroll")                                        \
        for (int j = 0; j < 6; ++j)                              \
            acc[j] += xv.x * wp[j]      + xv.y * wp[6 + j]       \
                    + xv.z * wp[12 + j] + xv.w * wp[18 + j];     \
    }

__global__ __launch_bounds__(TPB, 1) void hybrid_kernel(
    const float* __restrict__ inp,   // (B, 784)
    const float* __restrict__ dw,    // (784, 6) row-major
    const float* __restrict__ db,    // (6,)
    const float* __restrict__ qw,    // (15,)
    const float* __restrict__ ow,    // (6, 1)
    const float* __restrict__ ob,    // (1,)
    float* __restrict__ out,         // (B, 1)
    int B)
{
    const int row = blockIdx.x * TPB + threadIdx.x;
    if (row >= B) return;

    const float4* x4 = (const float4*)(inp + (size_t)row * 784);

    float acc[6] = {0.f, 0.f, 0.f, 0.f, 0.f, 0.f};
    float4 bufA[CH], bufB[CH];

    LOAD_CHUNK(bufA, 0)

    #pragma unroll
    for (int c = 1; c < NC; ++c) {
        if (c & 1) { LOAD_CHUNK(bufB, c) COMP_CHUNK(bufA, c - 1) }
        else       { LOAD_CHUNK(bufA, c) COMP_CHUNK(bufB, c - 1) }
    }
    COMP_CHUNK(bufB, NC - 1)          // NC-1 = 13 (odd) -> lives in bufB

    // ---- epilogue (once per row; all parameter loads are wave-uniform) ----
    float a[6];
    float hh = 0.f;
    #pragma unroll
    for (int j = 0; j < 6; ++j) {
        a[j] = acc[j] + db[j];
        hh += a[j] * a[j];
    }
    const float inv = rsqrtf(hh);     // hh==0 -> inf -> NaN downstream, matches ref
    #pragma unroll
    for (int j = 0; j < 6; ++j) a[j] *= inv;

    // PYRAMID_PAIRS: second index is always first+1
    const int PI[15] = {0,1,0,2,1,3,0,2,4,1,3,0,2,1,0};
    #pragma unroll
    for (int k = 0; k < 15; ++k) {
        const int i = PI[k];
        const float q = qw[k];
        const float c = __cosf(q), s = __sinf(q);
        const float ai = a[i], aj = a[i + 1];
        a[i]     = c * ai + s * aj;
        a[i + 1] = c * aj - s * ai;
    }

    float v = ob[0];
    #pragma unroll
    for (int j = 0; j < 6; ++j) {
        float z = 1.f - 2.f * a[j] * a[j];
        z = isnan(z) ? 0.f : z;       // jnp.where(isnan(z), 0, z)
        v += z * ow[j];
    }
    out[row] = 1.f / (1.f + __expf(-v));
}

extern "C" void kernel_launch(void* const* d_in, const int* in_sizes, int n_in,
                              void* d_out, int out_size, void* d_ws, size_t ws_size,
                              hipStream_t stream) {
    const float* inp = (const float*)d_in[0];
    const float* dw  = (const float*)d_in[1];
    const float* db  = (const float*)d_in[2];
    const float* qw  = (const float*)d_in[3];
    const float* ow  = (const float*)d_in[4];
    const float* ob  = (const float*)d_in[5];
    float* out = (float*)d_out;

    const int B = in_sizes[0] / 784;          // 65536
    const int blocks = (B + TPB - 1) / TPB;   // 1024 blocks, 64 rows each
    hybrid_kernel<<<blocks, TPB, 0, stream>>>(inp, dw, db, qw, ow, ob, out, B);
}